// Round 1
// baseline (143.120 us; speedup 1.0000x reference)
//
#include <hip/hip_runtime.h>
#include <hip/hip_fp16.h>

// SIREN, single fused kernel, fully register-resident, 128 points/wave.
// A=weights / B=activations: D[16 feat x 16 pt] = W[16,32] * X[32,16 pt].
// sigma(p)=16*((p>>2)&1)+4*(p>>3)+(p&3) k-permutation makes each lane's packed
// sin outputs BE the next layer's B-fragment (no LDS, no shuffles in the loop).
// sigma(8q+j) = {4q+j (j<4), 16+4q+(j-4) (j>=4)} -> a lane's A-fragment is two
// aligned float4 loads from the raw weight matrix, packed with v_cvt_pkrtz.
// So NO prep kernel and NO workspace: everything is built in-kernel from d_in.
// Weights single f16 (hi-only): adds ~2e-3 error, far under the 1.6e-2
// threshold. 30/(2pi) folded into weights/biases at load time.
//
// R12: phase-split scheduling. Previous version ran at VGPR=64 with the
// compiler serializing each t-chain (MFMA -> sins -> pack -> next MFMA),
// exposing MFMA/sin latency (VALUBusy 68%, 59us). Now each layer issues all
// 16 MFMAs first (c0[8]/c1[8] live), then all sins, then all packs; coord
// loads are hoisted ahead of all L0 compute. launch_bounds (256,3) raises
// the VGPR cap to ~168 (12 waves/CU, >= the ~11 measured resident) so the
// wider live set doesn't spill.

#define SINSCALE 4.774648292756860f   // 30/(2*pi)

typedef __attribute__((ext_vector_type(8))) _Float16 half8;
typedef __attribute__((ext_vector_type(2))) __fp16 fp16x2;
typedef __attribute__((ext_vector_type(4))) float f32x4;

union S16 { uint4 u4; half8 h; };
union PK { fp16x2 h2; unsigned int u; };

__device__ __forceinline__ float fast_sigmoid(float t) {
    float e = __builtin_amdgcn_exp2f(t * -1.4426950408889634f);
    return 1.0f / (1.0f + e);
}

__device__ __forceinline__ unsigned int pk2(float a, float b) {
    PK p; p.h2 = __builtin_amdgcn_cvt_pkrtz(a, b);
    return p.u;
}

// Build the sigma-permuted A-fragment (hi f16, RTZ) for feature rows m:
// slots j=0..3 <- W[m][4q+j]*S, j=4..7 <- W[m][16+4q+(j-4)]*S.
__device__ __forceinline__ uint4 build_frag(const float* __restrict__ W, int m, int q) {
    const float4 fa = *reinterpret_cast<const float4*>(&W[m * 32 + 4 * q]);
    const float4 fb = *reinterpret_cast<const float4*>(&W[m * 32 + 16 + 4 * q]);
    uint4 u;
    u.x = pk2(fa.x * SINSCALE, fa.y * SINSCALE);
    u.y = pk2(fa.z * SINSCALE, fa.w * SINSCALE);
    u.z = pk2(fb.x * SINSCALE, fb.y * SINSCALE);
    u.w = pk2(fb.z * SINSCALE, fb.w * SINSCALE);
    return u;
}

// Scaled bias vector for C/D rows 4q..4q+3 (+off)
__device__ __forceinline__ f32x4 bias_frag(const float* __restrict__ b, int off, int q) {
    const float4 t = *reinterpret_cast<const float4*>(&b[off + 4 * q]);
    f32x4 r = {t.x * SINSCALE, t.y * SINSCALE, t.z * SINSCALE, t.w * SINSCALE};
    return r;
}

__global__ __launch_bounds__(256, 3) void siren_mfma(
    const float* __restrict__ coords,
    const float* __restrict__ w0, const float* __restrict__ b0,
    const float* __restrict__ w1, const float* __restrict__ b1,
    const float* __restrict__ w2, const float* __restrict__ b2,
    const float* __restrict__ w3, const float* __restrict__ b3,
    const float* __restrict__ w4, const float* __restrict__ b4,
    const float* __restrict__ w5, const float* __restrict__ b5,
    const float* __restrict__ wf, const float* __restrict__ bfin,
    float* __restrict__ out, int n) {
    const int lane = (int)(threadIdx.x & 63);
    const int q = lane >> 4;
    const int nl = lane & 15;
    const int pbase = blockIdx.x * 512 + (int)(threadIdx.x >> 6) * 128;

    // ---- hoist ALL coord loads: 8 independent global_load_dwordx2 in flight
    float2 cxy[8];
#pragma unroll
    for (int t = 0; t < 8; ++t) {
        int ptc = min(pbase + 16 * t + nl, n - 1);
        cxy[t] = reinterpret_cast<const float2*>(coords)[ptc];
    }

    // ---- weight fragments for layers 1..5, built from raw matrices ----
    uint4 Af[4][2];
    Af[0][0] = build_frag(w1, nl, q);  Af[0][1] = build_frag(w1, 16 + nl, q);
    Af[1][0] = build_frag(w2, nl, q);  Af[1][1] = build_frag(w2, 16 + nl, q);
    Af[2][0] = build_frag(w3, nl, q);  Af[2][1] = build_frag(w3, 16 + nl, q);
    Af[3][0] = build_frag(w4, nl, q);  Af[3][1] = build_frag(w4, 16 + nl, q);
    const uint4 Af5 = build_frag(w5, nl, q);

    // ---- L0: 2 -> 32 directly in B-frag format (features sigma(8q+j)) ----
    const float4 wa = *reinterpret_cast<const float4*>(&w0[8 * q]);
    const float4 wb = *reinterpret_cast<const float4*>(&w0[8 * q + 4]);
    const float4 wc = *reinterpret_cast<const float4*>(&w0[32 + 8 * q]);
    const float4 wd = *reinterpret_cast<const float4*>(&w0[32 + 8 * q + 4]);
    const float4 ba = *reinterpret_cast<const float4*>(&b0[4 * q]);
    const float4 bc = *reinterpret_cast<const float4*>(&b0[16 + 4 * q]);
    float wxs[8] = {wa.x, wa.z, wb.x, wb.z, wc.x, wc.z, wd.x, wd.z};
    float wys[8] = {wa.y, wa.w, wb.y, wb.w, wc.y, wc.w, wd.y, wd.w};
    float bbs[8] = {ba.x, ba.y, ba.z, ba.w, bc.x, bc.y, bc.z, bc.w};
#pragma unroll
    for (int j = 0; j < 8; ++j) {
        wxs[j] *= SINSCALE;
        wys[j] *= SINSCALE;
        bbs[j] *= SINSCALE;
    }

    uint4 Bt[8];
#pragma unroll
    for (int t = 0; t < 8; ++t) {
        float s[8];
#pragma unroll
        for (int j = 0; j < 8; ++j)
            s[j] = __builtin_amdgcn_sinf(fmaf(wxs[j], cxy[t].x, fmaf(wys[j], cxy[t].y, bbs[j])));
        Bt[t].x = pk2(s[0], s[1]);
        Bt[t].y = pk2(s[2], s[3]);
        Bt[t].z = pk2(s[4], s[5]);
        Bt[t].w = pk2(s[6], s[7]);
    }

    // ---- middle layers 1..4: phase-split. All 16 MFMAs first (8 independent
    // t-chains in the matrix pipe), then all 64 sins (trans pipe), then packs.
    const float* Bs[4] = {b1, b2, b3, b4};
#pragma unroll
    for (int l = 0; l < 4; ++l) {
        S16 Ah0, Ah1;
        Ah0.u4 = Af[l][0];
        Ah1.u4 = Af[l][1];
        const f32x4 bv0 = bias_frag(Bs[l], 0, q);
        const f32x4 bv1 = bias_frag(Bs[l], 16, q);
        f32x4 c0[8], c1[8];
#pragma unroll
        for (int t = 0; t < 8; ++t) {
            S16 B;
            B.u4 = Bt[t];
            c0[t] = __builtin_amdgcn_mfma_f32_16x16x32_f16(Ah0.h, B.h, bv0, 0, 0, 0);
            c1[t] = __builtin_amdgcn_mfma_f32_16x16x32_f16(Ah1.h, B.h, bv1, 0, 0, 0);
        }
#pragma unroll
        for (int t = 0; t < 8; ++t) {
            Bt[t].x = pk2(__builtin_amdgcn_sinf(c0[t][0]), __builtin_amdgcn_sinf(c0[t][1]));
            Bt[t].y = pk2(__builtin_amdgcn_sinf(c0[t][2]), __builtin_amdgcn_sinf(c0[t][3]));
            Bt[t].z = pk2(__builtin_amdgcn_sinf(c1[t][0]), __builtin_amdgcn_sinf(c1[t][1]));
            Bt[t].w = pk2(__builtin_amdgcn_sinf(c1[t][2]), __builtin_amdgcn_sinf(c1[t][3]));
        }
    }

    // ---- L5 (32->16) + final (16->3): phase-split MFMA / sin / reduce ----
    {
        S16 Ah5;
        Ah5.u4 = Af5;
        const f32x4 bv5 = bias_frag(b5, 0, q);
        float4 wfl[3];
#pragma unroll
        for (int c = 0; c < 3; ++c)
            wfl[c] = *reinterpret_cast<const float4*>(&wf[c * 16 + 4 * q]);

        f32x4 c5[8];
#pragma unroll
        for (int t = 0; t < 8; ++t) {
            S16 B;
            B.u4 = Bt[t];
            c5[t] = __builtin_amdgcn_mfma_f32_16x16x32_f16(Ah5.h, B.h, bv5, 0, 0, 0);
        }

        float red[8][3];
#pragma unroll
        for (int t = 0; t < 8; ++t) {
            float h0 = __builtin_amdgcn_sinf(c5[t][0]);
            float h1 = __builtin_amdgcn_sinf(c5[t][1]);
            float h2 = __builtin_amdgcn_sinf(c5[t][2]);
            float h3 = __builtin_amdgcn_sinf(c5[t][3]);
#pragma unroll
            for (int c = 0; c < 3; ++c)
                red[t][c] = fmaf(wfl[c].x, h0, fmaf(wfl[c].y, h1,
                            fmaf(wfl[c].z, h2, wfl[c].w * h3)));
        }
        // butterfly over the 4 q-lanes sharing a point column
#pragma unroll
        for (int t = 0; t < 8; ++t)
#pragma unroll
            for (int c = 0; c < 3; ++c) {
                float v = red[t][c];
                v += __shfl_xor(v, 16, 64);
                v += __shfl_xor(v, 32, 64);
                red[t][c] = v;
            }
        // lane outputs two points: t=q (pts 0..63) and t=4+q (pts 64..127)
        float o0[3], o1[3];
#pragma unroll
        for (int c = 0; c < 3; ++c) {
            float v01 = (q & 1) ? red[1][c] : red[0][c];
            float v23 = (q & 1) ? red[3][c] : red[2][c];
            o0[c] = fast_sigmoid(((q & 2) ? v23 : v01) + bfin[c]);
            float w01 = (q & 1) ? red[5][c] : red[4][c];
            float w23 = (q & 1) ? red[7][c] : red[6][c];
            o1[c] = fast_sigmoid(((q & 2) ? w23 : w01) + bfin[c]);
        }
        const int p0 = pbase + 16 * q + nl;
        const int p1 = p0 + 64;
        if (p0 < n) {
            out[3 * p0 + 0] = o0[0];
            out[3 * p0 + 1] = o0[1];
            out[3 * p0 + 2] = o0[2];
        }
        if (p1 < n) {
            out[3 * p1 + 0] = o1[0];
            out[3 * p1 + 1] = o1[1];
            out[3 * p1 + 2] = o1[2];
        }
    }
}

extern "C" void kernel_launch(void* const* d_in, const int* in_sizes, int n_in,
                              void* d_out, int out_size, void* d_ws, size_t ws_size,
                              hipStream_t stream) {
    const float* coords = (const float*)d_in[0];
    const float* w0 = (const float*)d_in[1];
    const float* b0 = (const float*)d_in[2];
    const float* w1 = (const float*)d_in[3];
    const float* b1 = (const float*)d_in[4];
    const float* w2 = (const float*)d_in[5];
    const float* b2 = (const float*)d_in[6];
    const float* w3 = (const float*)d_in[7];
    const float* b3 = (const float*)d_in[8];
    const float* w4 = (const float*)d_in[9];
    const float* b4 = (const float*)d_in[10];
    const float* w5 = (const float*)d_in[11];
    const float* b5 = (const float*)d_in[12];
    const float* wf = (const float*)d_in[13];
    const float* bf = (const float*)d_in[14];
    float* out = (float*)d_out;

    const int n = in_sizes[0] / 2;

    siren_mfma<<<(n + 511) / 512, 256, 0, stream>>>(
        coords, w0, b0, w1, b1, w2, b2, w3, b3, w4, b4, w5, b5, wf, bf, out, n);
}